// Round 5
// baseline (3678.743 us; speedup 1.0000x reference)
//
#include <hip/hip_runtime.h>

// JANET layer: T=2048, B=64, I=256, H=256.
// Phase 1 (unchanged): xfh[row][0:512] = seq_row @ [W_f|W_h] + [b_f|b_h], fp16 workspace.
// Phase 2: MFMA recurrence, 16 batches/block (4 blocks), U persistent in AGPRs.
//   Round-4 post-mortem: __syncthreads() emits s_waitcnt vmcnt(0) before s_barrier,
//   draining the depth-2 x prefetch (and out-store acks) EVERY step (~1000cyc on the
//   serial path). Also ds_write_b16 of h was a 4-way bank conflict (1024 cyc/step).
//   Fixes: (1) raw s_barrier + lgkmcnt(0)-only wait (LDS is the only cross-thread
//   data; x/out are lane-private) -> prefetch gets real 2-step flight;
//   (2) swizzle SW(row)=((row&7)<<4)^(((row>>2)&3)<<5): conflict-free for BOTH the
//   A-frag ds_read_b128 (8 lanes/4-bank group, balanced) and the h ds_write_b16
//   (lk->bits5/6 bijective, l15->bits2-4: all 32 banks);
//   (3) precomputed LDS byte offsets + static offset:0/8192 buffer select.

#define T_STEPS 2048
#define BATCH   64
#define NCOL    512
#define MB      16      // batches per block = MFMA M

typedef _Float16 half_t;
typedef half_t f16x8  __attribute__((ext_vector_type(8)));
typedef half_t half4_t __attribute__((ext_vector_type(4)));
typedef float  f32x4  __attribute__((ext_vector_type(4)));

__device__ __forceinline__ float4 ld4(const float* p) { return *(const float4*)p; }
__device__ __forceinline__ void fma4(float4& acc, float s, const float4& v) {
  acc.x = fmaf(s, v.x, acc.x); acc.y = fmaf(s, v.y, acc.y);
  acc.z = fmaf(s, v.z, acc.z); acc.w = fmaf(s, v.w, acc.w);
}

__device__ __forceinline__ void store_xt(float* p, const float4& v) { *(float4*)p = v; }
__device__ __forceinline__ void store_xt(half_t* p, const float4& v) {
  half4_t h;
  h.x = (half_t)v.x; h.y = (half_t)v.y; h.z = (half_t)v.z; h.w = (half_t)v.w;
  *(half4_t*)p = h;   // 8B store, offsets are multiples of 4 elements
}
__device__ __forceinline__ float xload(const float* p) { return *p; }
__device__ __forceinline__ float xload(const half_t* p) { return (float)*p; }

// ---------------- Phase 1: input-projection GEMM (unchanged) ----------------
template <typename XT>
__global__ __launch_bounds__(256, 4)
void xproj_gemm(const float* __restrict__ seq,
                const float* __restrict__ Wf, const float* __restrict__ bf,
                const float* __restrict__ Wh, const float* __restrict__ bh,
                XT* __restrict__ xfh)
{
  __shared__ float As[32 * 132];   // A^T: [k][m], pitch 132
  __shared__ float Bs[32 * 132];   // B:   [k][n], pitch 132
  const int tid = threadIdx.x;
  const int mt = blockIdx.x >> 2;
  const int nt = blockIdx.x & 3;
  const int m0 = mt * 128;
  const int n0 = nt * 128;
  const int tm = tid >> 4;   // 0..15
  const int tn = tid & 15;   // 0..15

  float4 acc[8][2];
  #pragma unroll
  for (int i = 0; i < 8; ++i) {
    acc[i][0] = make_float4(0.f, 0.f, 0.f, 0.f);
    acc[i][1] = make_float4(0.f, 0.f, 0.f, 0.f);
  }

  const float* bsrc  = (n0 < 256) ? Wf : Wh;
  const int    bcol0 = (n0 < 256) ? n0 : (n0 - 256);

  for (int kt = 0; kt < 8; ++kt) {
    const int k0 = kt * 32;
    #pragma unroll
    for (int p = 0; p < 4; ++p) {
      int idx = p * 256 + tid;
      int r   = idx >> 3;   // 0..127
      int c4  = idx & 7;    // 0..7
      float4 v = ld4(seq + (size_t)(m0 + r) * 256 + k0 + c4 * 4);
      As[(c4*4+0)*132 + r] = v.x;
      As[(c4*4+1)*132 + r] = v.y;
      As[(c4*4+2)*132 + r] = v.z;
      As[(c4*4+3)*132 + r] = v.w;
    }
    #pragma unroll
    for (int p = 0; p < 4; ++p) {
      int idx = p * 256 + tid;
      int kr  = idx >> 5;   // 0..31
      int c4  = idx & 31;   // 0..31
      float4 v = ld4(bsrc + (size_t)(k0 + kr) * 256 + bcol0 + c4 * 4);
      *(float4*)&Bs[kr*132 + c4*4] = v;
    }
    __syncthreads();
    #pragma unroll
    for (int k = 0; k < 32; ++k) {
      float4 a0 = ld4(&As[k*132 + tm*4]);
      float4 a1 = ld4(&As[k*132 + 64 + tm*4]);
      float4 b0 = ld4(&Bs[k*132 + tn*4]);
      float4 b1 = ld4(&Bs[k*132 + 64 + tn*4]);
      float ar[8] = {a0.x, a0.y, a0.z, a0.w, a1.x, a1.y, a1.z, a1.w};
      #pragma unroll
      for (int i = 0; i < 8; ++i) {
        fma4(acc[i][0], ar[i], b0);
        fma4(acc[i][1], ar[i], b1);
      }
    }
    __syncthreads();
  }

  const float* bias_src = (n0 < 256) ? bf : bh;
  float4 bias0 = ld4(bias_src + bcol0 + tn*4);
  float4 bias1 = ld4(bias_src + bcol0 + 64 + tn*4);
  #pragma unroll
  for (int i = 0; i < 8; ++i) {
    int m = m0 + ((i < 4) ? (tm*4 + i) : (64 + tm*4 + (i - 4)));
    float4 r0 = acc[i][0];
    r0.x += bias0.x; r0.y += bias0.y; r0.z += bias0.z; r0.w += bias0.w;
    float4 r1 = acc[i][1];
    r1.x += bias1.x; r1.y += bias1.y; r1.z += bias1.z; r1.w += bias1.w;
    store_xt(xfh + (size_t)m * NCOL + n0 + tn*4,      r0);
    store_xt(xfh + (size_t)m * NCOL + n0 + 64 + tn*4, r1);
  }
}

// ---------------- Phase 2: MFMA recurrence ----------------
// 4 blocks x 512 threads (8 waves). Block handles batches [blockIdx*16, +16).
// Wave w: cols [w*32, w*32+32) of BOTH U_f (acc tiles 0-1) and U_h (tiles 2-3).
// B-frags (U, fp16) persistent: u[4][8] = 128 regs (AGPR half of unified file).
// MFMA 16x16x32_f16: A row = lane&15, k = (lane>>4)*8+e; B col = lane&15;
// C/D col = lane&15, row(batch) = (lane>>4)*4 + reg.
// LDS swizzle: phys(row,cb) = row*512 + (cb ^ SW(row)),
//   SW(row) = ((row&7)<<4) ^ (((row>>2)&3)<<5)   -- conflict-free reads AND writes.
template <typename XT>
__global__ __launch_bounds__(512, 2)
void janet_rec(const float* __restrict__ Uf, const float* __restrict__ Uh,
               const XT* __restrict__ xfh, const float* __restrict__ pa,
               float* __restrict__ out)
{
  // h double buffer: [2][16 rows][256 cols] fp16, row stride 512B, swizzled
  __shared__ __align__(16) half_t hbuf[2][MB * 256];
  const int tid  = threadIdx.x;
  const int wave = tid >> 6;
  const int lane = tid & 63;
  const int l15  = lane & 15;
  const int lk   = lane >> 4;          // 0..3
  const int wcol = wave * 32;          // wave's 32-col slice (same j for Uf & Uh)

  // ---- preload B fragments: u[nt][kt]; nt 0-1 = U_f, nt 2-3 = U_h
  f16x8 u[4][8];
  #pragma unroll
  for (int nt = 0; nt < 4; ++nt) {
    const float* Us = (nt < 2) ? Uf : Uh;
    const int col = wcol + (nt & 1) * 16 + l15;
    #pragma unroll
    for (int kt = 0; kt < 8; ++kt) {
      const int k0 = kt * 32 + lk * 8;
      f16x8 v;
      #pragma unroll
      for (int e = 0; e < 8; ++e) v[e] = (half_t)Us[(size_t)(k0 + e) * 256 + col];
      u[nt][kt] = v;
    }
  }

  const float aprelu = pa[0];
  const int b0 = lk * 4;               // C-reg row base (batch within block)

  // zero h buffer 0 (h_{-1} = 0): 512 threads x 8 halves = 4096
  {
    f16x8 z;
    #pragma unroll
    for (int e = 0; e < 8; ++e) z[e] = (half_t)0.f;
    *(f16x8*)&hbuf[0][tid * 8] = z;
  }

  float h_old[2][4];
  #pragma unroll
  for (int n = 0; n < 2; ++n)
    #pragma unroll
    for (int r = 0; r < 4; ++r) h_old[n][r] = 0.f;

  // per-C-row global pointers (x reads, out writes)
  const XT* xp[4];
  float*    op[4];
  #pragma unroll
  for (int r = 0; r < 4; ++r) {
    const int bg = blockIdx.x * MB + b0 + r;
    xp[r] = xfh + (size_t)bg * NCOL + wcol + l15;
    op[r] = out + (size_t)bg * 256  + wcol + l15;
  }

  // ---- precomputed swizzled LDS byte offsets (VGPR-resident, loop-invariant)
  // SW(row) = ((row&7)<<4) ^ (((row>>2)&3)<<5)
  int aoff[8];
  #pragma unroll
  for (int kt = 0; kt < 8; ++kt) {
    const int sw = ((l15 & 7) << 4) ^ (((l15 >> 2) & 3) << 5);
    aoff[kt] = l15 * 512 + ((lk * 16 + kt * 64) ^ sw);
  }
  int woff[2][4];
  #pragma unroll
  for (int n = 0; n < 2; ++n)
    #pragma unroll
    for (int r = 0; r < 4; ++r) {
      const int brow = b0 + r;
      const int sw = ((brow & 7) << 4) ^ (((brow >> 2) & 3) << 5);
      woff[n][r] = brow * 512 + (((wcol + n * 16 + l15) * 2) ^ sw);
    }

  // ---- depth-2 x prefetch: bank slot = r*4 + s, s in {0:xf n0, 1:xf n1, 2:xh n0, 3:xh n1}
  float xbA[16], xbB[16];
  #pragma unroll
  for (int r = 0; r < 4; ++r) {
    xbA[r*4+0] = xload(xp[r] + 0);
    xbA[r*4+1] = xload(xp[r] + 16);
    xbA[r*4+2] = xload(xp[r] + 256);
    xbA[r*4+3] = xload(xp[r] + 272);
    xp[r] += (size_t)BATCH * NCOL;
  }
  #pragma unroll
  for (int r = 0; r < 4; ++r) {
    xbB[r*4+0] = xload(xp[r] + 0);
    xbB[r*4+1] = xload(xp[r] + 16);
    xbB[r*4+2] = xload(xp[r] + 256);
    xbB[r*4+3] = xload(xp[r] + 272);
    xp[r] += (size_t)BATCH * NCOL;   // xp now points at t=2
  }

  const char* hb = (const char*)hbuf;
  __syncthreads();   // once: covers zero-fill (+ preload drain); full drain OK here

  // LDS-only barrier: writes drained (lgkmcnt), NO vmcnt drain (x/out are
  // lane-private). Compiler fences + sched_barrier pin code motion (rule #18).
#define JBARRIER()                                                \
  asm volatile("s_waitcnt lgkmcnt(0)" ::: "memory");              \
  __builtin_amdgcn_s_barrier();                                   \
  asm volatile("" ::: "memory");                                  \
  __builtin_amdgcn_sched_barrier(0)

  // One step. Reads h from buffer byte-offset PB, writes h_t to WB (literals!),
  // consumes x bank xb then refills it for t+2 (WAR orders refill after use).
#define JSTEP(t, xb, PB, WB)                                                    \
  {                                                                             \
    f32x4 acc[4];                                                               \
    _Pragma("unroll")                                                           \
    for (int nt = 0; nt < 4; ++nt) {                                            \
      acc[nt][0] = 0.f; acc[nt][1] = 0.f; acc[nt][2] = 0.f; acc[nt][3] = 0.f;   \
    }                                                                           \
    _Pragma("unroll")                                                           \
    for (int kt = 0; kt < 8; ++kt) {                                            \
      const f16x8 afrag = *(const f16x8*)(hb + aoff[kt] + (PB));                \
      _Pragma("unroll")                                                         \
      for (int nt = 0; nt < 4; ++nt)                                            \
        acc[nt] = __builtin_amdgcn_mfma_f32_16x16x32_f16(afrag, u[nt][kt],      \
                                                         acc[nt], 0, 0, 0);     \
    }                                                                           \
    _Pragma("unroll")                                                           \
    for (int n = 0; n < 2; ++n) {                                               \
      _Pragma("unroll")                                                         \
      for (int r = 0; r < 4; ++r) {                                             \
        const float pf = acc[n][r]     + xb[r*4 + n];                           \
        const float pg = acc[n + 2][r] + xb[r*4 + 2 + n];                       \
        const float f  = __builtin_amdgcn_rcpf(1.f + __expf(-pf));              \
        const float e2 = __expf(2.f * pg);                                      \
        const float g  = 1.f - 2.f * __builtin_amdgcn_rcpf(e2 + 1.f);           \
        float hn = fmaf(f, h_old[n][r] - g, g);                                 \
        hn = fmaf(aprelu, fminf(hn, 0.f), fmaxf(hn, 0.f));   /* prelu */        \
        h_old[n][r] = hn;                                                       \
        op[r][n * 16] = hn;                                                     \
        *(half_t*)((char*)hbuf + woff[n][r] + (WB)) = (half_t)hn;               \
      }                                                                         \
    }                                                                           \
    _Pragma("unroll")                                                           \
    for (int r = 0; r < 4; ++r) op[r] += (size_t)BATCH * 256;                   \
    if ((t) + 2 < T_STEPS) {                                                    \
      _Pragma("unroll")                                                         \
      for (int r = 0; r < 4; ++r) {                                             \
        xb[r*4+0] = xload(xp[r] + 0);                                           \
        xb[r*4+1] = xload(xp[r] + 16);                                          \
        xb[r*4+2] = xload(xp[r] + 256);                                         \
        xb[r*4+3] = xload(xp[r] + 272);                                         \
        xp[r] += (size_t)BATCH * NCOL;                                          \
      }                                                                         \
    }                                                                           \
    JBARRIER();                                                                 \
  }

  for (int t = 0; t < T_STEPS; t += 2) {
    JSTEP(t,     xbA, 0,    8192);
    JSTEP(t + 1, xbB, 8192, 0);
  }
#undef JSTEP
#undef JBARRIER
}

extern "C" void kernel_launch(void* const* d_in, const int* in_sizes, int n_in,
                              void* d_out, int out_size, void* d_ws, size_t ws_size,
                              hipStream_t stream) {
  const float* seq = (const float*)d_in[0];
  const float* Wf  = (const float*)d_in[1];
  const float* Uf  = (const float*)d_in[2];
  const float* bf  = (const float*)d_in[3];
  const float* Wh  = (const float*)d_in[4];
  const float* Uh  = (const float*)d_in[5];
  const float* bh  = (const float*)d_in[6];
  const float* pa  = (const float*)d_in[7];
  float* out = (float*)d_out;

  const size_t rows = (size_t)T_STEPS * BATCH;
  const size_t need_f32 = rows * NCOL * sizeof(float);   // 256 MiB

  dim3 g1(4096), blk1(256);
  dim3 g2(BATCH / MB), blk2(512);

  if (ws_size >= need_f32) {
    float* xfh = (float*)d_ws;
    hipLaunchKernelGGL(xproj_gemm<float>, g1, blk1, 0, stream, seq, Wf, bf, Wh, bh, xfh);
    hipLaunchKernelGGL(janet_rec<float>,  g2, blk2, 0, stream, Uf, Uh, xfh, pa, out);
  } else {
    half_t* xfh = (half_t*)d_ws;
    hipLaunchKernelGGL(xproj_gemm<half_t>, g1, blk1, 0, stream, seq, Wf, bf, Wh, bh, xfh);
    hipLaunchKernelGGL(janet_rec<half_t>,  g2, blk2, 0, stream, Uf, Uh, xfh, pa, out);
  }
}

// Round 6
// 2467.042 us; speedup vs baseline: 1.4912x; 1.4912x over previous
//
#include <hip/hip_runtime.h>

// JANET layer: T=2048, B=64, I=256, H=256.
// Phase 1 (unchanged): xfh[row][0:512] = seq_row @ [W_f|W_h] + [b_f|b_h], fp16 workspace.
// Phase 2: dot2 recurrence, 64 blocks (one per batch, 64 CUs) x 512 threads.
//   Post-mortem history: MFMA path (R2-R5) is stuck at ~3100us on 4 CUs and cannot
//   scale (M=16 tile + exec-masked combine). The R1 dot2 path used 64 CUs but:
//   (a) compiler chose VGPR=128 and demoted the 128-reg U slice to AGPRs
//       (v_dot2 can't read AGPRs -> extra move per dot2, ~2x inner-loop issue);
//   (b) h-reads were 4-way bank conflicts; (c) 2 barriers/step + cross-wave g swap.
//   This version: amdgpu_waves_per_eu(2,2) forces a 256-VGPR budget (U stays VGPR);
//   thread group (jg,kg) covers cols {Uf j0..j0+3, Uh j0..j0+3} so f and g for the
//   same j land in lanes kg / kg^4 of one wave -> one shfl_xor, ONE barrier/step,
//   shared exp+rcp for sigmoid/tanh; h stored chunk-rotated in LDS so the 4x
//   ds_read_b128 hit all 8 bank-quads (conflict-free); depth-2 x prefetch;
//   lgkm-only barrier (no vmcnt drain of prefetch/out-stores).

#define T_STEPS 2048
#define BATCH   64
#define NCOL    512

typedef _Float16 half_t;
typedef half_t half2_t __attribute__((ext_vector_type(2)));
typedef half_t half4_t __attribute__((ext_vector_type(4)));

__device__ __forceinline__ float4 ld4(const float* p) { return *(const float4*)p; }
__device__ __forceinline__ void fma4(float4& acc, float s, const float4& v) {
  acc.x = fmaf(s, v.x, acc.x); acc.y = fmaf(s, v.y, acc.y);
  acc.z = fmaf(s, v.z, acc.z); acc.w = fmaf(s, v.w, acc.w);
}

__device__ __forceinline__ void store_xt(float* p, const float4& v) { *(float4*)p = v; }
__device__ __forceinline__ void store_xt(half_t* p, const float4& v) {
  half4_t h;
  h.x = (half_t)v.x; h.y = (half_t)v.y; h.z = (half_t)v.z; h.w = (half_t)v.w;
  *(half4_t*)p = h;   // 8B store, offsets are multiples of 4 elements
}
__device__ __forceinline__ float xload(const float* p) { return *p; }
__device__ __forceinline__ float xload(const half_t* p) { return (float)*p; }

#if __has_builtin(__builtin_amdgcn_fdot2)
__device__ __forceinline__ float fdot2(half2_t a, half2_t b, float c) {
  return __builtin_amdgcn_fdot2(a, b, c, false);   // v_dot2_f32_f16
}
#else
__device__ __forceinline__ float fdot2(half2_t a, half2_t b, float c) {
  return c + (float)a.x * (float)b.x + (float)a.y * (float)b.y;
}
#endif

__device__ __forceinline__ half2_t bcast_h2(float f) {
  return __builtin_bit_cast(half2_t, f);
}

// ---------------- Phase 1: input-projection GEMM (unchanged) ----------------
template <typename XT>
__global__ __launch_bounds__(256, 4)
void xproj_gemm(const float* __restrict__ seq,
                const float* __restrict__ Wf, const float* __restrict__ bf,
                const float* __restrict__ Wh, const float* __restrict__ bh,
                XT* __restrict__ xfh)
{
  __shared__ float As[32 * 132];   // A^T: [k][m], pitch 132
  __shared__ float Bs[32 * 132];   // B:   [k][n], pitch 132
  const int tid = threadIdx.x;
  const int mt = blockIdx.x >> 2;
  const int nt = blockIdx.x & 3;
  const int m0 = mt * 128;
  const int n0 = nt * 128;
  const int tm = tid >> 4;   // 0..15
  const int tn = tid & 15;   // 0..15

  float4 acc[8][2];
  #pragma unroll
  for (int i = 0; i < 8; ++i) {
    acc[i][0] = make_float4(0.f, 0.f, 0.f, 0.f);
    acc[i][1] = make_float4(0.f, 0.f, 0.f, 0.f);
  }

  const float* bsrc  = (n0 < 256) ? Wf : Wh;
  const int    bcol0 = (n0 < 256) ? n0 : (n0 - 256);

  for (int kt = 0; kt < 8; ++kt) {
    const int k0 = kt * 32;
    #pragma unroll
    for (int p = 0; p < 4; ++p) {
      int idx = p * 256 + tid;
      int r   = idx >> 3;   // 0..127
      int c4  = idx & 7;    // 0..7
      float4 v = ld4(seq + (size_t)(m0 + r) * 256 + k0 + c4 * 4);
      As[(c4*4+0)*132 + r] = v.x;
      As[(c4*4+1)*132 + r] = v.y;
      As[(c4*4+2)*132 + r] = v.z;
      As[(c4*4+3)*132 + r] = v.w;
    }
    #pragma unroll
    for (int p = 0; p < 4; ++p) {
      int idx = p * 256 + tid;
      int kr  = idx >> 5;   // 0..31
      int c4  = idx & 31;   // 0..31
      float4 v = ld4(bsrc + (size_t)(k0 + kr) * 256 + bcol0 + c4 * 4);
      *(float4*)&Bs[kr*132 + c4*4] = v;
    }
    __syncthreads();
    #pragma unroll
    for (int k = 0; k < 32; ++k) {
      float4 a0 = ld4(&As[k*132 + tm*4]);
      float4 a1 = ld4(&As[k*132 + 64 + tm*4]);
      float4 b0 = ld4(&Bs[k*132 + tn*4]);
      float4 b1 = ld4(&Bs[k*132 + 64 + tn*4]);
      float ar[8] = {a0.x, a0.y, a0.z, a0.w, a1.x, a1.y, a1.z, a1.w};
      #pragma unroll
      for (int i = 0; i < 8; ++i) {
        fma4(acc[i][0], ar[i], b0);
        fma4(acc[i][1], ar[i], b1);
      }
    }
    __syncthreads();
  }

  const float* bias_src = (n0 < 256) ? bf : bh;
  float4 bias0 = ld4(bias_src + bcol0 + tn*4);
  float4 bias1 = ld4(bias_src + bcol0 + 64 + tn*4);
  #pragma unroll
  for (int i = 0; i < 8; ++i) {
    int m = m0 + ((i < 4) ? (tm*4 + i) : (64 + tm*4 + (i - 4)));
    float4 r0 = acc[i][0];
    r0.x += bias0.x; r0.y += bias0.y; r0.z += bias0.z; r0.w += bias0.w;
    float4 r1 = acc[i][1];
    r1.x += bias1.x; r1.y += bias1.y; r1.z += bias1.z; r1.w += bias1.w;
    store_xt(xfh + (size_t)m * NCOL + n0 + tn*4,      r0);
    store_xt(xfh + (size_t)m * NCOL + n0 + 64 + tn*4, r1);
  }
}

// ---------------- Phase 2: dot2 recurrence ----------------
// 64 blocks x 512 threads. Thread (jg=tid>>3, kg=tid&7):
//   columns i=0..7 -> {Uf[:,j0+i]}_{i<4} U {Uh[:,j0+i-4]}_{i>=4}, j0 = jg*4
//   k-slice [kg*32, kg*32+32): u2[8][16] half2 = 128 VGPRs (kept resident by
//   amdgpu_waves_per_eu(2,2): budget 256, no AGPR demotion).
// After the xor-reduce, lane kg holds the full-K dot for column i=kg:
//   kg<4 -> f-preact of j0+kg; kg>=4 -> g-preact of j0+kg-4. One shfl_xor(.,4)
//   pairs them; all lanes compute hn (dup x2); kg<4 writes h to LDS, kg>=4
//   writes out to global.
// h in LDS fp16, chunk-rotated: logical 16B chunk c=k>>3 -> phys ((c&3)<<3)|(c>>2);
//   thread kg reads 4x b128 at bytes kg*16 + i*128 -> per instruction the 8 kg
//   groups hit 8 distinct bank-quads (conflict-free; was 4-way in R1).
template <typename XT>
__global__ __launch_bounds__(512)
__attribute__((amdgpu_waves_per_eu(2, 2)))
void janet_rec(const float* __restrict__ Uf, const float* __restrict__ Uh,
               const XT* __restrict__ xfh, const float* __restrict__ pa,
               float* __restrict__ out)
{
  __shared__ __align__(16) half_t h_lds[256];
  const int tid = threadIdx.x;
  const int b   = blockIdx.x;
  const int kg  = tid & 7;
  const int jg  = tid >> 3;
  const int j0  = jg * 4;

  // ---- preload U slice (fp16 pairs): u2[i][p], k = kg*32 + 2p
  half2_t u2[8][16];
  #pragma unroll
  for (int i = 0; i < 8; ++i) {
    const float* Us = (i < 4) ? (Uf + j0 + i) : (Uh + j0 + i - 4);
    #pragma unroll
    for (int p = 0; p < 16; ++p) {
      const int k = kg * 32 + 2 * p;
      half2_t w;
      w.x = (half_t)Us[(size_t)k * 256];
      w.y = (half_t)Us[(size_t)(k + 1) * 256];
      u2[i][p] = w;
    }
  }

  const float aprelu = pa[0];

  // my x column (f-lanes read xf, g-lanes read xh) and my h/out column
  const int ocol = j0 + (kg & 3);
  const int xcol = (kg < 4) ? ocol : (256 + ocol);
  const XT* xp = xfh + (size_t)b * NCOL + xcol;
  float*   op  = out + (size_t)b * 256 + ocol;

  // reader base: 4x b128 at hrd + {0,128,256,384}
  const char* hrd = (const char*)h_lds + kg * 16;
  // writer byte offset for h[ocol] under the chunk rotation
  int wbyte;
  {
    const int c = ocol >> 3;
    const int P = ((c & 3) << 3) | (c >> 2);
    wbyte = (P * 8 + (ocol & 7)) * 2;
  }

  if (tid < 256) h_lds[tid] = (half_t)0.f;   // h_{-1}=0 -> step 0 is the general step
  float h_old = 0.f;

  // depth-2 x prefetch
  float xA = xload(xp); xp += (size_t)BATCH * NCOL;
  float xB = xload(xp); xp += (size_t)BATCH * NCOL;   // xp now at t=2

  asm volatile("s_waitcnt lgkmcnt(0)" ::: "memory");
  __builtin_amdgcn_s_barrier();
  asm volatile("" ::: "memory");

  // One step: h-read (4x b128) -> 128 dot2 -> 8-lane xor-reduce -> shared
  // exp/rcp activation -> f/g pair swap -> hn -> {ds_write h | out store} ->
  // x refill for t+2 -> lgkm-only barrier.
#define JSTEP(t, xb)                                                            \
  {                                                                             \
    const float4 q0 = *(const float4*)(hrd + 0);                                \
    const float4 q1 = *(const float4*)(hrd + 128);                              \
    const float4 q2 = *(const float4*)(hrd + 256);                              \
    const float4 q3 = *(const float4*)(hrd + 384);                              \
    half2_t hp[16];                                                             \
    hp[0]  = bcast_h2(q0.x); hp[1]  = bcast_h2(q0.y);                           \
    hp[2]  = bcast_h2(q0.z); hp[3]  = bcast_h2(q0.w);                           \
    hp[4]  = bcast_h2(q1.x); hp[5]  = bcast_h2(q1.y);                           \
    hp[6]  = bcast_h2(q1.z); hp[7]  = bcast_h2(q1.w);                           \
    hp[8]  = bcast_h2(q2.x); hp[9]  = bcast_h2(q2.y);                           \
    hp[10] = bcast_h2(q2.z); hp[11] = bcast_h2(q2.w);                           \
    hp[12] = bcast_h2(q3.x); hp[13] = bcast_h2(q3.y);                           \
    hp[14] = bcast_h2(q3.z); hp[15] = bcast_h2(q3.w);                           \
    float acc[8];                                                               \
    _Pragma("unroll")                                                           \
    for (int i = 0; i < 8; ++i) acc[i] = 0.f;                                   \
    _Pragma("unroll")                                                           \
    for (int p = 0; p < 16; ++p) {                                              \
      const half2_t hv = hp[p];                                                 \
      _Pragma("unroll")                                                         \
      for (int i = 0; i < 8; ++i) acc[i] = fdot2(hv, u2[i][p], acc[i]);         \
    }                                                                           \
    float s00 = acc[0] + __shfl_xor(acc[0], 1);                                 \
    float s01 = acc[1] + __shfl_xor(acc[1], 1);                                 \
    float s02 = acc[2] + __shfl_xor(acc[2], 1);                                 \
    float s03 = acc[3] + __shfl_xor(acc[3], 1);                                 \
    float s04 = acc[4] + __shfl_xor(acc[4], 1);                                 \
    float s05 = acc[5] + __shfl_xor(acc[5], 1);                                 \
    float s06 = acc[6] + __shfl_xor(acc[6], 1);                                 \
    float s07 = acc[7] + __shfl_xor(acc[7], 1);                                 \
    const bool sb0 = (kg & 1);                                                  \
    float r0 = sb0 ? s01 : s00;                                                 \
    float r1 = sb0 ? s03 : s02;                                                 \
    float r2 = sb0 ? s05 : s04;                                                 \
    float r3 = sb0 ? s07 : s06;                                                 \
    r0 += __shfl_xor(r0, 2);                                                    \
    r1 += __shfl_xor(r1, 2);                                                    \
    r2 += __shfl_xor(r2, 2);                                                    \
    r3 += __shfl_xor(r3, 2);                                                    \
    const bool sb1 = (kg & 2);                                                  \
    float t0 = sb1 ? r1 : r0;                                                   \
    float t1 = sb1 ? r3 : r2;                                                   \
    t0 += __shfl_xor(t0, 4);                                                    \
    t1 += __shfl_xor(t1, 4);                                                    \
    const float dsum = (kg & 4) ? t1 : t0;                                      \
    const float pre = dsum + xb;                                                \
    const float e   = __expf((kg < 4) ? -pre : 2.f * pre);                      \
    const float rr  = __builtin_amdgcn_rcpf(1.f + e);                           \
    const float val = (kg < 4) ? rr : fmaf(-2.f, rr, 1.f);                      \
    const float oth = __shfl_xor(val, 4);                                       \
    const float fg_f = (kg < 4) ? val : oth;                                    \
    const float fg_g = (kg < 4) ? oth : val;                                    \
    float hn = fmaf(fg_f, h_old - fg_g, fg_g);                                  \
    hn = fmaf(aprelu, fminf(hn, 0.f), fmaxf(hn, 0.f));   /* prelu */            \
    h_old = hn;                                                                 \
    if (kg < 4) *(half_t*)((char*)h_lds + wbyte) = (half_t)hn;                  \
    else        *op = hn;                                                       \
    op += (size_t)BATCH * 256;                                                  \
    if ((t) + 2 < T_STEPS) { xb = xload(xp); xp += (size_t)BATCH * NCOL; }      \
    asm volatile("s_waitcnt lgkmcnt(0)" ::: "memory");                          \
    __builtin_amdgcn_s_barrier();                                               \
    asm volatile("" ::: "memory");                                              \
  }

  for (int t = 0; t < T_STEPS; t += 2) {
    JSTEP(t,     xA);
    JSTEP(t + 1, xB);
  }
#undef JSTEP
}

extern "C" void kernel_launch(void* const* d_in, const int* in_sizes, int n_in,
                              void* d_out, int out_size, void* d_ws, size_t ws_size,
                              hipStream_t stream) {
  const float* seq = (const float*)d_in[0];
  const float* Wf  = (const float*)d_in[1];
  const float* Uf  = (const float*)d_in[2];
  const float* bf  = (const float*)d_in[3];
  const float* Wh  = (const float*)d_in[4];
  const float* Uh  = (const float*)d_in[5];
  const float* bh  = (const float*)d_in[6];
  const float* pa  = (const float*)d_in[7];
  float* out = (float*)d_out;

  const size_t rows = (size_t)T_STEPS * BATCH;
  const size_t need_f32 = rows * NCOL * sizeof(float);   // 256 MiB

  dim3 g1(4096), blk1(256);
  dim3 g2(BATCH), blk2(512);

  if (ws_size >= need_f32) {
    float* xfh = (float*)d_ws;
    hipLaunchKernelGGL(xproj_gemm<float>, g1, blk1, 0, stream, seq, Wf, bf, Wh, bh, xfh);
    hipLaunchKernelGGL(janet_rec<float>,  g2, blk2, 0, stream, Uf, Uh, xfh, pa, out);
  } else {
    half_t* xfh = (half_t*)d_ws;
    hipLaunchKernelGGL(xproj_gemm<half_t>, g1, blk1, 0, stream, seq, Wf, bf, Wh, bh, xfh);
    hipLaunchKernelGGL(janet_rec<half_t>,  g2, blk2, 0, stream, Uf, Uh, xfh, pa, out);
  }
}